// Round 10
// baseline (213.029 us; speedup 1.0000x reference)
//
#include <hip/hip_runtime.h>
#include <hip/hip_bf16.h>

#define S_LEN   2048
#define HID     1024
#define NH      16
#define HD      64
#define WIN     512
#define NW      4
#define NG      64
#define GSTRIDE 32
#define SCALE   0.125f   // 64^-0.5

typedef __bf16 bf16x8 __attribute__((ext_vector_type(8)));
typedef float  f32x4  __attribute__((ext_vector_type(4)));
typedef unsigned short ushort_t;

// ---------------- fp32 -> bf16 helpers ----------------
__device__ __forceinline__ ushort_t f32_to_bf16_rne(float f) {
    unsigned int u = __float_as_uint(f);
    u = u + 0x7FFFu + ((u >> 16) & 1u);
    return (ushort_t)(u >> 16);
}
__device__ __forceinline__ float bf16_to_f32(ushort_t h) {
    return __uint_as_float(((unsigned int)h) << 16);
}

// ---------------- batched cast: 5 tensors fp32 -> bf16 in one launch ----------------
struct CastJobs {
    const float* in[5];
    ushort_t* hi[5];
    int n4[5];
};

__global__ __launch_bounds__(256) void cast_all_kernel(CastJobs jobs) {
    int j = blockIdx.y;
    int i = blockIdx.x * 256 + threadIdx.x;
    if (i >= jobs.n4[j]) return;
    float4 f = ((const float4*)jobs.in[j])[i];
    ushort4 h;
    h.x = f32_to_bf16_rne(f.x);
    h.y = f32_to_bf16_rne(f.y);
    h.z = f32_to_bf16_rne(f.z);
    h.w = f32_to_bf16_rne(f.w);
    ((ushort4*)jobs.hi[j])[i] = h;
}

// ============== LDS-free MFMA GEMM (flatmm style) ==============
// Every MFMA fragment (A[m=lane&15][k=quad*8+j], B likewise) is 16 B/lane and
// 64 B-contiguous per 4-lane quad -> loaded DIRECTLY global->register.
// No LDS, no barriers; 1-deep register prefetch overlaps next step's loads
// with this step's MFMAs; L2 serves the heavy cross-block operand reuse.

// --- QKV variant: 3 weight segments; bf16 q/k outputs + transposed bf16 V ---
__global__ __launch_bounds__(128) void gemm_qkv_kernel(
    const ushort_t* __restrict__ xb,
    const ushort_t* __restrict__ wqb, const float* __restrict__ bq,
    const ushort_t* __restrict__ wkb, const float* __restrict__ bk,
    const ushort_t* __restrict__ wvb, const float* __restrict__ bv,
    ushort_t* __restrict__ qb, ushort_t* __restrict__ kb,
    ushort_t* __restrict__ vtb)
{
    const int tid  = threadIdx.x;
    const int lane = tid & 63;
    const int w    = tid >> 6;
    const int quad = lane >> 4, lm = lane & 15;
    const int seg  = blockIdx.x >> 4;
    const int bn   = (blockIdx.x & 15) * 64;
    const int bm   = blockIdx.y * 128;

    const ushort_t* B  = (seg == 0) ? wqb : (seg == 1) ? wkb : wvb;
    const float* bias  = (seg == 0) ? bq  : (seg == 1) ? bk  : bv;

    const ushort_t* ap[4];
    const ushort_t* bp[4];
#pragma unroll
    for (int i = 0; i < 4; ++i)
        ap[i] = &xb[(size_t)(bm + w * 64 + i * 16 + lm) * HID + quad * 8];
#pragma unroll
    for (int j = 0; j < 4; ++j)
        bp[j] = &B[(size_t)(bn + j * 16 + lm) * HID + quad * 8];

    f32x4 acc[4][4];
#pragma unroll
    for (int i = 0; i < 4; ++i)
#pragma unroll
        for (int j = 0; j < 4; ++j) acc[i][j] = {0.f, 0.f, 0.f, 0.f};

    bf16x8 af[2][4], bf[2][4];
#pragma unroll
    for (int i = 0; i < 4; ++i) af[0][i] = *(const bf16x8*)ap[i];
#pragma unroll
    for (int j = 0; j < 4; ++j) bf[0][j] = *(const bf16x8*)bp[j];

    for (int it = 0; it < 32; ++it) {
        int cur = it & 1, nxt = cur ^ 1;
        if (it < 31) {
            int k1 = (it + 1) * 32;
#pragma unroll
            for (int i = 0; i < 4; ++i) af[nxt][i] = *(const bf16x8*)(ap[i] + k1);
#pragma unroll
            for (int j = 0; j < 4; ++j) bf[nxt][j] = *(const bf16x8*)(bp[j] + k1);
        }
#pragma unroll
        for (int i = 0; i < 4; ++i)
#pragma unroll
            for (int j = 0; j < 4; ++j)
                acc[i][j] = __builtin_amdgcn_mfma_f32_16x16x32_bf16(af[cur][i], bf[cur][j], acc[i][j], 0, 0, 0);
    }

    // epilogue: C/D layout col=lane&15, row=quad*4+reg
#pragma unroll
    for (int i = 0; i < 4; ++i)
#pragma unroll
        for (int j = 0; j < 4; ++j) {
            int col = bn + j * 16 + lm;
            float b = bias[col];
            int row0 = bm + w * 64 + i * 16 + quad * 4;
            if (seg == 2) {
                // transposed V: r=0..3 are consecutive jj -> one 8B store
                int hh = col >> 6, dd = col & 63, nn = row0 >> 9, jj = row0 & 511;
                ushort4 v4;
                v4.x = f32_to_bf16_rne(acc[i][j][0] + b);
                v4.y = f32_to_bf16_rne(acc[i][j][1] + b);
                v4.z = f32_to_bf16_rne(acc[i][j][2] + b);
                v4.w = f32_to_bf16_rne(acc[i][j][3] + b);
                *(ushort4*)&vtb[(((size_t)nn * NH + hh) * HD + dd) * WIN + jj] = v4;
            } else {
                ushort_t* dst = (seg == 0) ? qb : kb;
#pragma unroll
                for (int r = 0; r < 4; ++r)
                    dst[(size_t)(row0 + r) * HID + col] = f32_to_bf16_rne(acc[i][j][r] + b);
            }
        }
}

// --- out-proj: 64x64 x K=1024, fused bias, LDS-free, fp32 out ---
__global__ __launch_bounds__(128) void gemm_out_kernel(
    const ushort_t* __restrict__ A, const ushort_t* __restrict__ B,
    const float* __restrict__ bias, float* __restrict__ out)
{
    const int tid  = threadIdx.x;
    const int lane = tid & 63;
    const int w    = tid >> 6;
    const int quad = lane >> 4, lm = lane & 15;
    const int bn   = blockIdx.x * 64;
    const int bm   = blockIdx.y * 64;

    const ushort_t* ap[2];
    const ushort_t* bp[4];
#pragma unroll
    for (int i = 0; i < 2; ++i)
        ap[i] = &A[(size_t)(bm + w * 32 + i * 16 + lm) * HID + quad * 8];
#pragma unroll
    for (int j = 0; j < 4; ++j)
        bp[j] = &B[(size_t)(bn + j * 16 + lm) * HID + quad * 8];

    f32x4 acc[2][4];
#pragma unroll
    for (int i = 0; i < 2; ++i)
#pragma unroll
        for (int j = 0; j < 4; ++j) acc[i][j] = {0.f, 0.f, 0.f, 0.f};

    bf16x8 af[2][2], bf[2][4];
#pragma unroll
    for (int i = 0; i < 2; ++i) af[0][i] = *(const bf16x8*)ap[i];
#pragma unroll
    for (int j = 0; j < 4; ++j) bf[0][j] = *(const bf16x8*)bp[j];

    for (int it = 0; it < 32; ++it) {
        int cur = it & 1, nxt = cur ^ 1;
        if (it < 31) {
            int k1 = (it + 1) * 32;
#pragma unroll
            for (int i = 0; i < 2; ++i) af[nxt][i] = *(const bf16x8*)(ap[i] + k1);
#pragma unroll
            for (int j = 0; j < 4; ++j) bf[nxt][j] = *(const bf16x8*)(bp[j] + k1);
        }
#pragma unroll
        for (int i = 0; i < 2; ++i)
#pragma unroll
            for (int j = 0; j < 4; ++j)
                acc[i][j] = __builtin_amdgcn_mfma_f32_16x16x32_bf16(af[cur][i], bf[cur][j], acc[i][j], 0, 0, 0);
    }

#pragma unroll
    for (int i = 0; i < 2; ++i)
#pragma unroll
        for (int j = 0; j < 4; ++j) {
            int col = bn + j * 16 + lm;
            float b = bias[col];
#pragma unroll
            for (int r = 0; r < 4; ++r) {
                int row = bm + w * 32 + i * 16 + quad * 4 + r;
                out[(size_t)row * HID + col] = acc[i][j][r] + b;
            }
        }
}

// ---------------- V sums from transposed bf16 V: wave per (n,h,d) row ----------------
__global__ __launch_bounds__(256) void vsum_kernel(const ushort_t* __restrict__ vtb,
    float* __restrict__ vwin, float* __restrict__ vgwin)
{
    int wid  = blockIdx.x * 4 + (threadIdx.x >> 6);   // 0..4095 = (n*NH+h)*HD+d
    int lane = threadIdx.x & 63;
    bf16x8 v = *(const bf16x8*)&vtb[(size_t)wid * WIN + lane * 8];
    float s = 0.f;
#pragma unroll
    for (int e = 0; e < 8; ++e) s += (float)v[e];
    float sg = ((lane & 3) == 0) ? (float)v[0] : 0.f;  // j = lane*8, j%32==0 iff lane%4==0
#pragma unroll
    for (int off = 1; off < 64; off <<= 1) {
        s  += __shfl_xor(s,  off);
        sg += __shfl_xor(sg, off);
    }
    if (lane == 0) { vwin[wid] = s; vgwin[wid] = sg; }
}

// ---------------- MFMA flash attention: S^T formulation, barrier-free ----------------
// Grid (16 qtiles of 32, 16 heads, 4 windows) = 1024 blocks, 128 thr = 2 waves.
// K and Vt fragments load DIRECTLY global->register (L2-hot: 64 KB K + 64 KB
// Vt per block, shared across 16 blocks per (n,h)); the only LDS use is the
// wave-private P round-trip (C-layout -> A-layout), which needs no barrier.
// The main loop contains ZERO __syncthreads -> nothing blocks load hoisting,
// and ~10 waves/CU of occupancy hides L2 latency.
__global__ __launch_bounds__(128) void attn_mfma_kernel(
    const ushort_t* __restrict__ qb, const ushort_t* __restrict__ kb,
    const ushort_t* __restrict__ vtb,
    const float* __restrict__ vwin, const float* __restrict__ vgwin,
    ushort_t* __restrict__ ath)
{
    __shared__ __align__(16) ushort_t sP[2][16 * 68]; // per-wave P[q][key], 68-padded rows
    __shared__ float sPe[48];
    __shared__ float sAe[64];
    __shared__ float sLe0;

    const int tid  = threadIdx.x;
    const int lane = tid & 63;
    const int w    = tid >> 6;     // 0..1
    const int quad = lane >> 4;
    const int lm   = lane & 15;
    const int tile = blockIdx.x;   // 0..15
    const int h    = blockIdx.y;
    const int n    = blockIdx.z;

    const ushort_t* kbase = &kb[(size_t)(n * WIN) * HID + h * HD];
    const ushort_t* vbase = &vtb[(size_t)(n * NH + h) * HD * WIN];

    const size_t qrow = (size_t)(n * WIN + tile * 32 + w * 16 + lm);
    const bf16x8 aq0 = *(const bf16x8*)&qb[qrow * HID + h * HD + quad * 8];
    const bf16x8 aq1 = *(const bf16x8*)&qb[qrow * HID + h * HD + 32 + quad * 8];

    // per-lane K row base (row = lm within each 16-key group) and Vt row base
    const ushort_t* kp = &kbase[(size_t)lm * HID + quad * 8];

    f32x4 acc[4];
#pragma unroll
    for (int dt = 0; dt < 4; ++dt) acc[dt] = {0.f, 0.f, 0.f, 0.f};
    float lac = 0.f;                       // denominator partial for query lm
    // query global <=> (tile*32 + w*16 + lm) % 32 == 0 <=> w==0 && lm==0
    const bool qgl = (w == 0) && (lm == 0);

    ushort_t* sPw = sP[w];

    for (int c = 0; c < 8; ++c) {
        // ---- S^T = K.Q^T + softmax numerators (shift m=0 safe: |s| < ~4) ----
#pragma unroll
        for (int jt = 0; jt < 4; ++jt) {
            const ushort_t* kr = kp + (size_t)(c * 64 + jt * 16) * HID;
            bf16x8 ak0 = *(const bf16x8*)kr;
            bf16x8 ak1 = *(const bf16x8*)(kr + 32);
            f32x4 s = {0.f, 0.f, 0.f, 0.f};
            s = __builtin_amdgcn_mfma_f32_16x16x32_bf16(ak0, aq0, s, 0, 0, 0);
            s = __builtin_amdgcn_mfma_f32_16x16x32_bf16(ak1, aq1, s, 0, 0, 0);
            // s[r]: key = c*64 + jt*16 + quad*4 + r, query = lm
            const bool kg = ((jt & 1) == 0) && (quad == 0);  // key%32==0 needs r==0 too
            ushort4 p4;
#pragma unroll
            for (int r = 0; r < 4; ++r) {
                float sv = s[r] * SCALE;
                if (qgl && kg && r == 0) sv += sv;   // in-window global pair: 2x score
                float p = __expf(sv);
                ushort_t ph = f32_to_bf16_rne(p);
                lac += bf16_to_f32(ph);
                ((ushort_t*)&p4)[r] = ph;
            }
            // P[q=lm][key=jt*16+quad*4 .. +3] -> one 8B LDS store
            *(ushort4*)&sPw[lm * 68 + jt * 16 + quad * 4] = p4;
        }

        // ---- PV: P (A-layout, contiguous row read; same-wave lgkm dep) x Vt ----
        bf16x8 pf[2];
        pf[0] = *(const bf16x8*)&sPw[lm * 68 + quad * 8];
        pf[1] = *(const bf16x8*)&sPw[lm * 68 + 32 + quad * 8];
#pragma unroll
        for (int dt = 0; dt < 4; ++dt) {
            const ushort_t* vr = vbase + (size_t)(dt * 16 + lm) * WIN + c * 64;
#pragma unroll
            for (int jc = 0; jc < 2; ++jc) {
                bf16x8 vf = *(const bf16x8*)(vr + (jc * 4 + quad) * 8);
                acc[dt] = __builtin_amdgcn_mfma_f32_16x16x32_bf16(pf[jc], vf, acc[dt], 0, 0, 0);
            }
        }
    }

    // ---- denominator: reduce over the 4 quads (each covered disjoint keys) ----
    float lred = lac;
    lred += __shfl_xor(lred, 16);
    lred += __shfl_xor(lred, 32);   // all lanes with same lm now hold l[query=lm]

    // ---- out-of-window global keys for the 1 global query of this block ----
    __syncthreads();
    if (tid < 48) {
        int kk = tid;
        int g = kk + (kk >= n * 16 ? 16 : 0);   // skip in-window globals
        const ushort_t* qr = &qb[(size_t)(n * WIN + tile * 32) * HID + h * HD];
        const ushort_t* kr = &kb[(size_t)(g * GSTRIDE) * HID + h * HD];
        float dot = 0.f;
#pragma unroll
        for (int dc = 0; dc < 8; ++dc) {
            bf16x8 qv = *(const bf16x8*)&qr[dc * 8];
            bf16x8 kv = *(const bf16x8*)&kr[dc * 8];
#pragma unroll
            for (int e = 0; e < 8; ++e) dot += (float)qv[e] * (float)kv[e];
        }
        sPe[tid] = __expf(dot * SCALE);
    }
    __syncthreads();
    if (tid < 64) {
        int d = tid;
        float a = 0.f;
        for (int kk = 0; kk < 48; ++kk) {
            int g = kk + (kk >= n * 16 ? 16 : 0);
            int gwin = g >> 4, jj = (g & 15) * GSTRIDE;
            a += sPe[kk] *
                 bf16_to_f32(vtb[((size_t)(gwin * NH + h) * HD + d) * WIN + jj]);
        }
        sAe[d] = a;
    } else if (tid == 64) {
        float s = 0.f;
        for (int kk = 0; kk < 48; ++kk) s += sPe[kk];
        sLe0 = s;
    }
    __syncthreads();

    // ---- vrest inline from the vwin/vgwin tables (16 KB, L1-hot) ----
    float vr_ng_r[4], vr_g_r[4];
#pragma unroll
    for (int dt = 0; dt < 4; ++dt) {
        int d = dt * 16 + lm;
        float vall = 0.f, vgall = 0.f;
#pragma unroll
        for (int n2 = 0; n2 < NW; ++n2) {
            vall  += vwin [(n2 * NH + h) * HD + d];
            vgall += vgwin[(n2 * NH + h) * HD + d];
        }
        float w_  = vwin [(n * NH + h) * HD + d];
        float gw_ = vgwin[(n * NH + h) * HD + d];
        vr_ng_r[dt] = vall - w_;
        vr_g_r[dt]  = vall - w_ - (vgall - gw_);
    }

    // ---- epilogue: fold zero-score keys, normalize, write bf16 ----
#pragma unroll
    for (int r = 0; r < 4; ++r) {
        int qo = w * 16 + quad * 4 + r;
        int qwin = tile * 32 + qo;
        bool isg = ((qwin & (GSTRIDE - 1)) == 0);
        float lr = __shfl(lred, quad * 4 + r);     // l for this output row's query
        float l = lr + (float)(S_LEN - WIN);       // exp(0)=1 per non-attended key
        if (isg) l += sLe0 - 48.0f;                // 48 attended keys replace zeros
        float invl = 1.f / l;
        size_t row = (size_t)(n * WIN + qwin) * HID + h * HD;
#pragma unroll
        for (int dt = 0; dt < 4; ++dt) {
            int d = dt * 16 + lm;
            float o = acc[dt][r] + (isg ? (vr_g_r[dt] + sAe[d]) : vr_ng_r[dt]);
            ath[row + d] = f32_to_bf16_rne(o * invl);
        }
    }
}

extern "C" void kernel_launch(void* const* d_in, const int* in_sizes, int n_in,
                              void* d_out, int out_size, void* d_ws, size_t ws_size,
                              hipStream_t stream) {
    const float* x   = (const float*)d_in[0];
    const float* wq  = (const float*)d_in[1];
    const float* bq  = (const float*)d_in[2];
    const float* wk  = (const float*)d_in[3];
    const float* bk_ = (const float*)d_in[4];
    const float* wv  = (const float*)d_in[5];
    const float* bv  = (const float*)d_in[6];
    const float* wo  = (const float*)d_in[7];
    const float* bo  = (const float*)d_in[8];
    float* out = (float*)d_out;

    const size_t M2 = 2u * 1024 * 1024, M1 = 1024 * 1024;
    float* ws = (float*)d_ws;
    float* vwin  = ws;                       // 4096 floats
    float* vgwin = vwin + NW * NH * HD;      // 4096 floats
    ushort_t* us = (ushort_t*)(ws + 16384);
    ushort_t* xb  = us;            // 4 MB
    ushort_t* wqb = xb + M2;       ushort_t* wkb = wqb + M1;
    ushort_t* wvb = wkb + M1;      ushort_t* wob = wvb + M1;
    ushort_t* qb  = wob + M1;      // 4 MB
    ushort_t* kb  = qb + M2;       // 4 MB
    ushort_t* vtb = kb + M2;       // 4 MB
    ushort_t* ath = vtb + M2;      // 4 MB

    CastJobs jobs;
    jobs.in[0] = x;  jobs.hi[0] = xb;  jobs.n4[0] = (int)(M2 / 4);
    jobs.in[1] = wq; jobs.hi[1] = wqb; jobs.n4[1] = (int)(M1 / 4);
    jobs.in[2] = wk; jobs.hi[2] = wkb; jobs.n4[2] = (int)(M1 / 4);
    jobs.in[3] = wv; jobs.hi[3] = wvb; jobs.n4[3] = (int)(M1 / 4);
    jobs.in[4] = wo; jobs.hi[4] = wob; jobs.n4[4] = (int)(M1 / 4);
    cast_all_kernel<<<dim3(2048, 5), 256, 0, stream>>>(jobs);

    // fused QKV: 128x64 blocks, grid (3 segs x 16 cols) x 16 rows = 768 blocks
    gemm_qkv_kernel<<<dim3(48, 16), 128, 0, stream>>>(
        xb, wqb, bq, wkb, bk_, wvb, bv, qb, kb, vtb);

    // V sums from vtb: 4096 waves, one per (n,h,d) row
    vsum_kernel<<<1024, 256, 0, stream>>>(vtb, vwin, vgwin);

    // attention: 1024 blocks, 128 threads, barrier-free main loop
    attn_mfma_kernel<<<dim3(16, NH, NW), 128, 0, stream>>>(
        qb, kb, vtb, vwin, vgwin, ath);

    // out projection: 64x64 x K=1024 + fused bias, 512 blocks
    gemm_out_kernel<<<dim3(16, 32), 128, 0, stream>>>(ath, wob, bo, out);
}

// Round 11
// 155.240 us; speedup vs baseline: 1.3723x; 1.3723x over previous
//
#include <hip/hip_runtime.h>
#include <hip/hip_bf16.h>

#define S_LEN   2048
#define HID     1024
#define NH      16
#define HD      64
#define WIN     512
#define NW      4
#define NG      64
#define GSTRIDE 32
#define SCALE   0.125f   // 64^-0.5

typedef __bf16 bf16x8 __attribute__((ext_vector_type(8)));
typedef float  f32x4  __attribute__((ext_vector_type(4)));
typedef unsigned short ushort_t;

// ---------------- fp32 -> bf16 helpers ----------------
__device__ __forceinline__ ushort_t f32_to_bf16_rne(float f) {
    unsigned int u = __float_as_uint(f);
    u = u + 0x7FFFu + ((u >> 16) & 1u);
    return (ushort_t)(u >> 16);
}
__device__ __forceinline__ float bf16_to_f32(ushort_t h) {
    return __uint_as_float(((unsigned int)h) << 16);
}

// ---------------- batched cast: 5 tensors fp32 -> bf16 in one launch ----------------
struct CastJobs {
    const float* in[5];
    ushort_t* hi[5];
    int n4[5];
};

__global__ __launch_bounds__(256) void cast_all_kernel(CastJobs jobs) {
    int j = blockIdx.y;
    int i = blockIdx.x * 256 + threadIdx.x;
    if (i >= jobs.n4[j]) return;
    float4 f = ((const float4*)jobs.in[j])[i];
    ushort4 h;
    h.x = f32_to_bf16_rne(f.x);
    h.y = f32_to_bf16_rne(f.y);
    h.z = f32_to_bf16_rne(f.z);
    h.w = f32_to_bf16_rne(f.w);
    ((ushort4*)jobs.hi[j])[i] = h;
}

// ---------------- async global -> LDS (16B per lane) ----------------
__device__ __forceinline__ void async16(const ushort_t* g, ushort_t* l) {
    __builtin_amdgcn_global_load_lds(
        (const __attribute__((address_space(1))) void*)g,
        (__attribute__((address_space(3))) void*)l, 16, 0, 0);
}

// ============== single-bf16 MFMA GEMM (LDS-staged; round-9 structure) ==============
// R10 lesson: fragment-direct global loads are UNcoalesced (lane stride = 2KB)
// -> 4x L2 traffic, MfmaUtil 8%. LDS staging converts coalesced global reads
// into the strided fragment pattern; keep it.

// --- QKV variant, BK=64: halves barrier/drain rounds vs BK=32 at unchanged
// occupancy (LDS 24 KB, grid 768 = 3 blocks/CU). Row = 128 B -> swizzle
// gc = kp ^ (row & 7); fragment slot = (koff/8 + quad) ^ (row & 7) -> 2-way
// bank aliasing (free), staging permutes within one 128 B line (coalesced).
__global__ __launch_bounds__(128) void gemm_qkv_kernel(
    const ushort_t* __restrict__ xb,
    const ushort_t* __restrict__ wqb, const float* __restrict__ bq,
    const ushort_t* __restrict__ wkb, const float* __restrict__ bk,
    const ushort_t* __restrict__ wvb, const float* __restrict__ bv,
    ushort_t* __restrict__ qb, ushort_t* __restrict__ kb,
    ushort_t* __restrict__ vtb)
{
    __shared__ ushort_t sA[128 * 64];   // 16 KB
    __shared__ ushort_t sB[64 * 64];    //  8 KB
    const int tid  = threadIdx.x;
    const int lane = tid & 63;
    const int w    = tid >> 6;
    const int quad = lane >> 4, lm = lane & 15;
    const int seg  = blockIdx.x >> 4;
    const int bn   = (blockIdx.x & 15) * 64;
    const int bm   = blockIdx.y * 128;

    const ushort_t* B  = (seg == 0) ? wqb : (seg == 1) ? wkb : wvb;
    const float* bias  = (seg == 0) ? bq  : (seg == 1) ? bk  : bv;

    f32x4 acc[4][4];
#pragma unroll
    for (int i = 0; i < 4; ++i)
#pragma unroll
        for (int j = 0; j < 4; ++j) acc[i][j] = {0.f, 0.f, 0.f, 0.f};

    for (int k0 = 0; k0 < HID; k0 += 64) {
        __syncthreads();
#pragma unroll
        for (int t = 0; t < 8; ++t) {          // A: 1024 chunks, 8/thread
            int c = tid + t * 128;
            int row = c >> 3, kp = c & 7, gc = kp ^ (row & 7);
            async16(&xb[(size_t)(bm + row) * HID + k0 + gc * 8], &sA[c * 8]);
        }
#pragma unroll
        for (int t = 0; t < 4; ++t) {          // B: 512 chunks, 4/thread
            int c = tid + t * 128;
            int row = c >> 3, kp = c & 7, gc = kp ^ (row & 7);
            async16(&B[(size_t)(bn + row) * HID + k0 + gc * 8], &sB[c * 8]);
        }
        asm volatile("s_waitcnt vmcnt(0)" ::: "memory");
        __syncthreads();

        // two BK=32 sub-steps per staged tile
#pragma unroll
        for (int sub = 0; sub < 2; ++sub) {
            bf16x8 af[4], bf[4];
#pragma unroll
            for (int i = 0; i < 4; ++i) {
                int row = w * 64 + i * 16 + lm;
                int slot = (sub * 4 + quad) ^ (row & 7);
                af[i] = *(const bf16x8*)&sA[row * 64 + slot * 8];
            }
#pragma unroll
            for (int j = 0; j < 4; ++j) {
                int row = j * 16 + lm;
                int slot = (sub * 4 + quad) ^ (row & 7);
                bf[j] = *(const bf16x8*)&sB[row * 64 + slot * 8];
            }
#pragma unroll
            for (int i = 0; i < 4; ++i)
#pragma unroll
                for (int j = 0; j < 4; ++j)
                    acc[i][j] = __builtin_amdgcn_mfma_f32_16x16x32_bf16(af[i], bf[j], acc[i][j], 0, 0, 0);
        }
    }

    // epilogue: C/D layout col=lane&15, row=quad*4+reg
#pragma unroll
    for (int i = 0; i < 4; ++i)
#pragma unroll
        for (int j = 0; j < 4; ++j) {
            int col = bn + j * 16 + lm;
            float b = bias[col];
            int row0 = bm + w * 64 + i * 16 + quad * 4;
            if (seg == 2) {
                // transposed V: r=0..3 are consecutive jj -> one 8B store
                int hh = col >> 6, dd = col & 63, nn = row0 >> 9, jj = row0 & 511;
                ushort4 v4;
                v4.x = f32_to_bf16_rne(acc[i][j][0] + b);
                v4.y = f32_to_bf16_rne(acc[i][j][1] + b);
                v4.z = f32_to_bf16_rne(acc[i][j][2] + b);
                v4.w = f32_to_bf16_rne(acc[i][j][3] + b);
                *(ushort4*)&vtb[(((size_t)nn * NH + hh) * HD + dd) * WIN + jj] = v4;
            } else {
                ushort_t* dst = (seg == 0) ? qb : kb;
#pragma unroll
                for (int r = 0; r < 4; ++r)
                    dst[(size_t)(row0 + r) * HID + col] = f32_to_bf16_rne(acc[i][j][r] + b);
            }
        }
}

// --- out-proj: direct 64x64 x K=1024 with fused bias, fp32 out (round-9) ---
__global__ __launch_bounds__(128) void gemm_out_kernel(
    const ushort_t* __restrict__ A, const ushort_t* __restrict__ B,
    const float* __restrict__ bias, float* __restrict__ out)
{
    __shared__ ushort_t sA[64 * 32];
    __shared__ ushort_t sB[64 * 32];
    const int tid  = threadIdx.x;
    const int lane = tid & 63;
    const int w    = tid >> 6;
    const int quad = lane >> 4, lm = lane & 15;
    const int bn   = blockIdx.x * 64;
    const int bm   = blockIdx.y * 64;

    f32x4 acc[2][4];   // wave tile 32x64
#pragma unroll
    for (int i = 0; i < 2; ++i)
#pragma unroll
        for (int j = 0; j < 4; ++j) acc[i][j] = {0.f, 0.f, 0.f, 0.f};

    for (int k0 = 0; k0 < HID; k0 += 32) {
        __syncthreads();
#pragma unroll
        for (int t = 0; t < 2; ++t) {
            int c = tid + t * 128;
            int row = c >> 2, kp = c & 3, gc = kp ^ ((row >> 1) & 3);
            async16(&A[(size_t)(bm + row) * HID + k0 + gc * 8], &sA[c * 8]);
            async16(&B[(size_t)(bn + row) * HID + k0 + gc * 8], &sB[c * 8]);
        }
        asm volatile("s_waitcnt vmcnt(0)" ::: "memory");
        __syncthreads();

        bf16x8 af[2], bf[4];
#pragma unroll
        for (int i = 0; i < 2; ++i) {
            int row = w * 32 + i * 16 + lm;
            int slot = quad ^ ((row >> 1) & 3);
            af[i] = *(const bf16x8*)&sA[row * 32 + slot * 8];
        }
#pragma unroll
        for (int j = 0; j < 4; ++j) {
            int row = j * 16 + lm;
            int slot = quad ^ ((row >> 1) & 3);
            bf[j] = *(const bf16x8*)&sB[row * 32 + slot * 8];
        }
#pragma unroll
        for (int i = 0; i < 2; ++i)
#pragma unroll
            for (int j = 0; j < 4; ++j)
                acc[i][j] = __builtin_amdgcn_mfma_f32_16x16x32_bf16(af[i], bf[j], acc[i][j], 0, 0, 0);
    }

#pragma unroll
    for (int i = 0; i < 2; ++i)
#pragma unroll
        for (int j = 0; j < 4; ++j) {
            int col = bn + j * 16 + lm;
            float b = bias[col];
#pragma unroll
            for (int r = 0; r < 4; ++r) {
                int row = bm + w * 32 + i * 16 + quad * 4 + r;
                out[(size_t)row * HID + col] = acc[i][j][r] + b;
            }
        }
}

// ---------------- V sums from transposed bf16 V: wave per (n,h,d) row ----------------
__global__ __launch_bounds__(256) void vsum_kernel(const ushort_t* __restrict__ vtb,
    float* __restrict__ vwin, float* __restrict__ vgwin)
{
    int wid  = blockIdx.x * 4 + (threadIdx.x >> 6);   // 0..4095 = (n*NH+h)*HD+d
    int lane = threadIdx.x & 63;
    bf16x8 v = *(const bf16x8*)&vtb[(size_t)wid * WIN + lane * 8];
    float s = 0.f;
#pragma unroll
    for (int e = 0; e < 8; ++e) s += (float)v[e];
    float sg = ((lane & 3) == 0) ? (float)v[0] : 0.f;  // j = lane*8, j%32==0 iff lane%4==0
#pragma unroll
    for (int off = 1; off < 64; off <<= 1) {
        s  += __shfl_xor(s,  off);
        sg += __shfl_xor(sg, off);
    }
    if (lane == 0) { vwin[wid] = s; vgwin[wid] = sg; }
}

// ---------------- MFMA flash attention: S^T formulation (round-9, best) ----------------
// Grid (16 qtiles of 32, 16 heads, 4 windows) = 1024 blocks, 128 thr = 2 waves.
// S^T = K.Q^T (operand swap): C-layout gives each lane 4 CONSECUTIVE keys of
// one query -> P stores are one ds_write_b64 per jt. PV reads row-major P as
// a contiguous b128 A-fragment.
__global__ __launch_bounds__(128) void attn_mfma_kernel(
    const ushort_t* __restrict__ qb, const ushort_t* __restrict__ kb,
    const ushort_t* __restrict__ vtb,
    const float* __restrict__ vwin, const float* __restrict__ vgwin,
    ushort_t* __restrict__ ath)
{
    __shared__ __align__(16) ushort_t sK[64 * 64];    // [key][8 chunks of 8 d], swizzled
    __shared__ __align__(16) ushort_t sVt[64 * 64];   // [d][8 chunks of 8 j], swizzled
    __shared__ __align__(16) ushort_t sP[2][16 * 68]; // per-wave P[q][key], 68-padded rows
    __shared__ float sPe[48];
    __shared__ float sAe[64];
    __shared__ float sLe0;

    const int tid  = threadIdx.x;
    const int lane = tid & 63;
    const int w    = tid >> 6;     // 0..1
    const int quad = lane >> 4;
    const int lm   = lane & 15;
    const int tile = blockIdx.x;   // 0..15
    const int h    = blockIdx.y;
    const int n    = blockIdx.z;

    const ushort_t* kbase = &kb[(size_t)(n * WIN) * HID + h * HD];
    const ushort_t* vbase = &vtb[(size_t)(n * NH + h) * HD * WIN];

    const size_t qrow = (size_t)(n * WIN + tile * 32 + w * 16 + lm);
    const bf16x8 aq0 = *(const bf16x8*)&qb[qrow * HID + h * HD + quad * 8];
    const bf16x8 aq1 = *(const bf16x8*)&qb[qrow * HID + h * HD + 32 + quad * 8];

    f32x4 acc[4];
#pragma unroll
    for (int dt = 0; dt < 4; ++dt) acc[dt] = {0.f, 0.f, 0.f, 0.f};
    float lac = 0.f;                       // denominator partial for query lm
    // query global <=> (tile*32 + w*16 + lm) % 32 == 0 <=> w==0 && lm==0
    const bool qgl = (w == 0) && (lm == 0);

    ushort_t* sPw = sP[w];

    for (int c = 0; c < 8; ++c) {
        __syncthreads();
        // stage 64 keys of K + 64 d-rows of Vt: 512 chunks each, 4/thread each
#pragma unroll
        for (int t = 0; t < 4; ++t) {
            int c2 = tid + t * 128;
            int key = c2 >> 3, ck = c2 & 7, gc = ck ^ (key & 7);
            async16(&kbase[(size_t)(c * 64 + key) * HID + gc * 8], &sK[c2 * 8]);
            int dd = c2 >> 3, sl = c2 & 7, gj = sl ^ (dd & 7);
            async16(&vbase[(size_t)dd * WIN + c * 64 + gj * 8], &sVt[c2 * 8]);
        }
        asm volatile("s_waitcnt vmcnt(0)" ::: "memory");
        __syncthreads();

        // ---- S^T = K.Q^T + softmax numerators (shift m=0 safe: |s| < ~4) ----
#pragma unroll
        for (int jt = 0; jt < 4; ++jt) {
            int key = jt * 16 + lm;
            bf16x8 ak0 = *(const bf16x8*)&sK[key * 64 + ((quad) ^ (key & 7)) * 8];
            bf16x8 ak1 = *(const bf16x8*)&sK[key * 64 + ((4 + quad) ^ (key & 7)) * 8];
            f32x4 s = {0.f, 0.f, 0.f, 0.f};
            s = __builtin_amdgcn_mfma_f32_16x16x32_bf16(ak0, aq0, s, 0, 0, 0);
            s = __builtin_amdgcn_mfma_f32_16x16x32_bf16(ak1, aq1, s, 0, 0, 0);
            // s[r]: key = jt*16 + quad*4 + r, query = lm
            const bool kg = ((jt & 1) == 0) && (quad == 0);  // key%32==0 needs r==0 too
            ushort4 p4;
#pragma unroll
            for (int r = 0; r < 4; ++r) {
                float sv = s[r] * SCALE;
                if (qgl && kg && r == 0) sv += sv;   // in-window global pair: 2x score
                float p = __expf(sv);
                ushort_t ph = f32_to_bf16_rne(p);
                lac += bf16_to_f32(ph);
                ((ushort_t*)&p4)[r] = ph;
            }
            // P[q=lm][key=jt*16+quad*4 .. +3] -> one 8B LDS store
            *(ushort4*)&sPw[lm * 68 + jt * 16 + quad * 4] = p4;
        }

        // ---- PV: P (A-layout, contiguous row read) x Vt (B-layout) ----
        bf16x8 pf[2];
        pf[0] = *(const bf16x8*)&sPw[lm * 68 + quad * 8];
        pf[1] = *(const bf16x8*)&sPw[lm * 68 + 32 + quad * 8];
#pragma unroll
        for (int dt = 0; dt < 4; ++dt) {
            int d = dt * 16 + lm;
#pragma unroll
            for (int jc = 0; jc < 2; ++jc) {
                bf16x8 vf = *(const bf16x8*)&sVt[d * 64 + (((jc * 4 + quad) ^ (d & 7))) * 8];
                acc[dt] = __builtin_amdgcn_mfma_f32_16x16x32_bf16(pf[jc], vf, acc[dt], 0, 0, 0);
            }
        }
    }

    // ---- denominator: reduce over the 4 quads (each covered disjoint keys) ----
    float lred = lac;
    lred += __shfl_xor(lred, 16);
    lred += __shfl_xor(lred, 32);   // all lanes with same lm now hold l[query=lm]

    // ---- out-of-window global keys for the 1 global query of this block ----
    __syncthreads();
    if (tid < 48) {
        int kk = tid;
        int g = kk + (kk >= n * 16 ? 16 : 0);   // skip in-window globals
        const ushort_t* qr = &qb[(size_t)(n * WIN + tile * 32) * HID + h * HD];
        const ushort_t* kr = &kb[(size_t)(g * GSTRIDE) * HID + h * HD];
        float dot = 0.f;
#pragma unroll
        for (int dc = 0; dc < 8; ++dc) {
            bf16x8 qv = *(const bf16x8*)&qr[dc * 8];
            bf16x8 kv = *(const bf16x8*)&kr[dc * 8];
#pragma unroll
            for (int e = 0; e < 8; ++e) dot += (float)qv[e] * (float)kv[e];
        }
        sPe[tid] = __expf(dot * SCALE);
    }
    __syncthreads();
    if (tid < 64) {
        int d = tid;
        float a = 0.f;
        for (int kk = 0; kk < 48; ++kk) {
            int g = kk + (kk >= n * 16 ? 16 : 0);
            int gwin = g >> 4, jj = (g & 15) * GSTRIDE;
            a += sPe[kk] *
                 bf16_to_f32(vtb[((size_t)(gwin * NH + h) * HD + d) * WIN + jj]);
        }
        sAe[d] = a;
    } else if (tid == 64) {
        float s = 0.f;
        for (int kk = 0; kk < 48; ++kk) s += sPe[kk];
        sLe0 = s;
    }
    __syncthreads();

    // ---- vrest inline from the vwin/vgwin tables (16 KB, L1-hot) ----
    float vr_ng_r[4], vr_g_r[4];
#pragma unroll
    for (int dt = 0; dt < 4; ++dt) {
        int d = dt * 16 + lm;
        float vall = 0.f, vgall = 0.f;
#pragma unroll
        for (int n2 = 0; n2 < NW; ++n2) {
            vall  += vwin [(n2 * NH + h) * HD + d];
            vgall += vgwin[(n2 * NH + h) * HD + d];
        }
        float w_  = vwin [(n * NH + h) * HD + d];
        float gw_ = vgwin[(n * NH + h) * HD + d];
        vr_ng_r[dt] = vall - w_;
        vr_g_r[dt]  = vall - w_ - (vgall - gw_);
    }

    // ---- epilogue: fold zero-score keys, normalize, write bf16 ----
#pragma unroll
    for (int r = 0; r < 4; ++r) {
        int qo = w * 16 + quad * 4 + r;
        int qwin = tile * 32 + qo;
        bool isg = ((qwin & (GSTRIDE - 1)) == 0);
        float lr = __shfl(lred, quad * 4 + r);     // l for this output row's query
        float l = lr + (float)(S_LEN - WIN);       // exp(0)=1 per non-attended key
        if (isg) l += sLe0 - 48.0f;                // 48 attended keys replace zeros
        float invl = 1.f / l;
        size_t row = (size_t)(n * WIN + qwin) * HID + h * HD;
#pragma unroll
        for (int dt = 0; dt < 4; ++dt) {
            int d = dt * 16 + lm;
            float o = acc[dt][r] + (isg ? (vr_g_r[dt] + sAe[d]) : vr_ng_r[dt]);
            ath[row + d] = f32_to_bf16_rne(o * invl);
        }
    }
}

extern "C" void kernel_launch(void* const* d_in, const int* in_sizes, int n_in,
                              void* d_out, int out_size, void* d_ws, size_t ws_size,
                              hipStream_t stream) {
    const float* x   = (const float*)d_in[0];
    const float* wq  = (const float*)d_in[1];
    const float* bq  = (const float*)d_in[2];
    const float* wk  = (const float*)d_in[3];
    const float* bk_ = (const float*)d_in[4];
    const float* wv  = (const float*)d_in[5];
    const float* bv  = (const float*)d_in[6];
    const float* wo  = (const float*)d_in[7];
    const float* bo  = (const float*)d_in[8];
    float* out = (float*)d_out;

    const size_t M2 = 2u * 1024 * 1024, M1 = 1024 * 1024;
    float* ws = (float*)d_ws;
    float* vwin  = ws;                       // 4096 floats
    float* vgwin = vwin + NW * NH * HD;      // 4096 floats
    ushort_t* us = (ushort_t*)(ws + 16384);
    ushort_t* xb  = us;            // 4 MB
    ushort_t* wqb = xb + M2;       ushort_t* wkb = wqb + M1;
    ushort_t* wvb = wkb + M1;      ushort_t* wob = wvb + M1;
    ushort_t* qb  = wob + M1;      // 4 MB
    ushort_t* kb  = qb + M2;       // 4 MB
    ushort_t* vtb = kb + M2;       // 4 MB
    ushort_t* ath = vtb + M2;      // 4 MB

    CastJobs jobs;
    jobs.in[0] = x;  jobs.hi[0] = xb;  jobs.n4[0] = (int)(M2 / 4);
    jobs.in[1] = wq; jobs.hi[1] = wqb; jobs.n4[1] = (int)(M1 / 4);
    jobs.in[2] = wk; jobs.hi[2] = wkb; jobs.n4[2] = (int)(M1 / 4);
    jobs.in[3] = wv; jobs.hi[3] = wvb; jobs.n4[3] = (int)(M1 / 4);
    jobs.in[4] = wo; jobs.hi[4] = wob; jobs.n4[4] = (int)(M1 / 4);
    cast_all_kernel<<<dim3(2048, 5), 256, 0, stream>>>(jobs);

    // fused QKV: 128x64 blocks, BK=64, grid (3 segs x 16 cols) x 16 rows = 768 blocks
    gemm_qkv_kernel<<<dim3(48, 16), 128, 0, stream>>>(
        xb, wqb, bq, wkb, bk_, wvb, bv, qb, kb, vtb);

    // V sums from vtb: 4096 waves, one per (n,h,d) row
    vsum_kernel<<<1024, 256, 0, stream>>>(vtb, vwin, vgwin);

    // attention: 1024 blocks (4/CU), 128 threads
    attn_mfma_kernel<<<dim3(16, NH, NW), 128, 0, stream>>>(
        qb, kb, vtb, vwin, vgwin, ath);

    // out projection: 64x64 x K=1024 + fused bias, 512 blocks (2/CU)
    gemm_out_kernel<<<dim3(16, 32), 128, 0, stream>>>(ath, wob, bo, out);
}

// Round 12
// 151.403 us; speedup vs baseline: 1.4070x; 1.0253x over previous
//
#include <hip/hip_runtime.h>
#include <hip/hip_bf16.h>

#define S_LEN   2048
#define HID     1024
#define NH      16
#define HD      64
#define WIN     512
#define NW      4
#define NG      64
#define GSTRIDE 32
#define SCALE   0.125f               // 64^-0.5
#define SCALE_LOG2E 0.180336880f    // 0.125 * log2(e)

#if __has_builtin(__builtin_amdgcn_exp2f)
#define EXP2F(x) __builtin_amdgcn_exp2f(x)
#else
#define EXP2F(x) __expf((x) * 0.6931471805599453f)
#endif

typedef __bf16 bf16x8 __attribute__((ext_vector_type(8)));
typedef float  f32x4  __attribute__((ext_vector_type(4)));
typedef unsigned short ushort_t;

// ---------------- fp32 -> bf16 helpers ----------------
__device__ __forceinline__ ushort_t f32_to_bf16_rne(float f) {
    unsigned int u = __float_as_uint(f);
    u = u + 0x7FFFu + ((u >> 16) & 1u);
    return (ushort_t)(u >> 16);
}
__device__ __forceinline__ float bf16_to_f32(ushort_t h) {
    return __uint_as_float(((unsigned int)h) << 16);
}

// ---------------- batched cast: 5 tensors fp32 -> bf16 in one launch ----------------
struct CastJobs {
    const float* in[5];
    ushort_t* hi[5];
    int n4[5];
};

__global__ __launch_bounds__(256) void cast_all_kernel(CastJobs jobs) {
    int j = blockIdx.y;
    int i = blockIdx.x * 256 + threadIdx.x;
    if (i >= jobs.n4[j]) return;
    float4 f = ((const float4*)jobs.in[j])[i];
    ushort4 h;
    h.x = f32_to_bf16_rne(f.x);
    h.y = f32_to_bf16_rne(f.y);
    h.z = f32_to_bf16_rne(f.z);
    h.w = f32_to_bf16_rne(f.w);
    ((ushort4*)jobs.hi[j])[i] = h;
}

// ---------------- async global -> LDS (16B per lane) ----------------
__device__ __forceinline__ void async16(const ushort_t* g, ushort_t* l) {
    __builtin_amdgcn_global_load_lds(
        (const __attribute__((address_space(1))) void*)g,
        (__attribute__((address_space(3))) void*)l, 16, 0, 0);
}

// ============== single-bf16 MFMA GEMM (LDS-staged) ==============
// R10 lesson: fragment-direct global loads are UNcoalesced (lane stride = 2KB)
// -> 4x L2 traffic. LDS staging converts coalesced global reads into the
// strided fragment pattern; keep it.

// --- QKV variant, BK=64 (R11 win): row = 128 B -> swizzle gc = kp ^ (row & 7);
// fragment slot = (sub*4 + quad) ^ (row & 7) -> 2-way bank aliasing (free).
__global__ __launch_bounds__(128) void gemm_qkv_kernel(
    const ushort_t* __restrict__ xb,
    const ushort_t* __restrict__ wqb, const float* __restrict__ bq,
    const ushort_t* __restrict__ wkb, const float* __restrict__ bk,
    const ushort_t* __restrict__ wvb, const float* __restrict__ bv,
    ushort_t* __restrict__ qb, ushort_t* __restrict__ kb,
    ushort_t* __restrict__ vtb)
{
    __shared__ ushort_t sA[128 * 64];   // 16 KB
    __shared__ ushort_t sB[64 * 64];    //  8 KB
    const int tid  = threadIdx.x;
    const int lane = tid & 63;
    const int w    = tid >> 6;
    const int quad = lane >> 4, lm = lane & 15;
    const int seg  = blockIdx.x >> 4;
    const int bn   = (blockIdx.x & 15) * 64;
    const int bm   = blockIdx.y * 128;

    const ushort_t* B  = (seg == 0) ? wqb : (seg == 1) ? wkb : wvb;
    const float* bias  = (seg == 0) ? bq  : (seg == 1) ? bk  : bv;

    f32x4 acc[4][4];
#pragma unroll
    for (int i = 0; i < 4; ++i)
#pragma unroll
        for (int j = 0; j < 4; ++j) acc[i][j] = {0.f, 0.f, 0.f, 0.f};

    for (int k0 = 0; k0 < HID; k0 += 64) {
        __syncthreads();
#pragma unroll
        for (int t = 0; t < 8; ++t) {          // A: 1024 chunks, 8/thread
            int c = tid + t * 128;
            int row = c >> 3, kp = c & 7, gc = kp ^ (row & 7);
            async16(&xb[(size_t)(bm + row) * HID + k0 + gc * 8], &sA[c * 8]);
        }
#pragma unroll
        for (int t = 0; t < 4; ++t) {          // B: 512 chunks, 4/thread
            int c = tid + t * 128;
            int row = c >> 3, kp = c & 7, gc = kp ^ (row & 7);
            async16(&B[(size_t)(bn + row) * HID + k0 + gc * 8], &sB[c * 8]);
        }
        asm volatile("s_waitcnt vmcnt(0)" ::: "memory");
        __syncthreads();

        // two BK=32 sub-steps per staged tile
#pragma unroll
        for (int sub = 0; sub < 2; ++sub) {
            bf16x8 af[4], bf[4];
#pragma unroll
            for (int i = 0; i < 4; ++i) {
                int row = w * 64 + i * 16 + lm;
                int slot = (sub * 4 + quad) ^ (row & 7);
                af[i] = *(const bf16x8*)&sA[row * 64 + slot * 8];
            }
#pragma unroll
            for (int j = 0; j < 4; ++j) {
                int row = j * 16 + lm;
                int slot = (sub * 4 + quad) ^ (row & 7);
                bf[j] = *(const bf16x8*)&sB[row * 64 + slot * 8];
            }
#pragma unroll
            for (int i = 0; i < 4; ++i)
#pragma unroll
                for (int j = 0; j < 4; ++j)
                    acc[i][j] = __builtin_amdgcn_mfma_f32_16x16x32_bf16(af[i], bf[j], acc[i][j], 0, 0, 0);
        }
    }

    // epilogue: C/D layout col=lane&15, row=quad*4+reg
#pragma unroll
    for (int i = 0; i < 4; ++i)
#pragma unroll
        for (int j = 0; j < 4; ++j) {
            int col = bn + j * 16 + lm;
            float b = bias[col];
            int row0 = bm + w * 64 + i * 16 + quad * 4;
            if (seg == 2) {
                // transposed V: r=0..3 are consecutive jj -> one 8B store
                int hh = col >> 6, dd = col & 63, nn = row0 >> 9, jj = row0 & 511;
                ushort4 v4;
                v4.x = f32_to_bf16_rne(acc[i][j][0] + b);
                v4.y = f32_to_bf16_rne(acc[i][j][1] + b);
                v4.z = f32_to_bf16_rne(acc[i][j][2] + b);
                v4.w = f32_to_bf16_rne(acc[i][j][3] + b);
                *(ushort4*)&vtb[(((size_t)nn * NH + hh) * HD + dd) * WIN + jj] = v4;
            } else {
                ushort_t* dst = (seg == 0) ? qb : kb;
#pragma unroll
                for (int r = 0; r < 4; ++r)
                    dst[(size_t)(row0 + r) * HID + col] = f32_to_bf16_rne(acc[i][j][r] + b);
            }
        }
}

// --- out-proj: 64x64 x K=1024, BK=64, fused bias, fp32 out ---
__global__ __launch_bounds__(128) void gemm_out_kernel(
    const ushort_t* __restrict__ A, const ushort_t* __restrict__ B,
    const float* __restrict__ bias, float* __restrict__ out)
{
    __shared__ ushort_t sA[64 * 64];   // 8 KB
    __shared__ ushort_t sB[64 * 64];   // 8 KB
    const int tid  = threadIdx.x;
    const int lane = tid & 63;
    const int w    = tid >> 6;
    const int quad = lane >> 4, lm = lane & 15;
    const int bn   = blockIdx.x * 64;
    const int bm   = blockIdx.y * 64;

    f32x4 acc[2][4];   // wave tile 32x64
#pragma unroll
    for (int i = 0; i < 2; ++i)
#pragma unroll
        for (int j = 0; j < 4; ++j) acc[i][j] = {0.f, 0.f, 0.f, 0.f};

    for (int k0 = 0; k0 < HID; k0 += 64) {
        __syncthreads();
#pragma unroll
        for (int t = 0; t < 4; ++t) {          // A,B: 512 chunks each, 4/thread
            int c = tid + t * 128;
            int row = c >> 3, kp = c & 7, gc = kp ^ (row & 7);
            async16(&A[(size_t)(bm + row) * HID + k0 + gc * 8], &sA[c * 8]);
            async16(&B[(size_t)(bn + row) * HID + k0 + gc * 8], &sB[c * 8]);
        }
        asm volatile("s_waitcnt vmcnt(0)" ::: "memory");
        __syncthreads();

#pragma unroll
        for (int sub = 0; sub < 2; ++sub) {
            bf16x8 af[2], bf[4];
#pragma unroll
            for (int i = 0; i < 2; ++i) {
                int row = w * 32 + i * 16 + lm;
                int slot = (sub * 4 + quad) ^ (row & 7);
                af[i] = *(const bf16x8*)&sA[row * 64 + slot * 8];
            }
#pragma unroll
            for (int j = 0; j < 4; ++j) {
                int row = j * 16 + lm;
                int slot = (sub * 4 + quad) ^ (row & 7);
                bf[j] = *(const bf16x8*)&sB[row * 64 + slot * 8];
            }
#pragma unroll
            for (int i = 0; i < 2; ++i)
#pragma unroll
                for (int j = 0; j < 4; ++j)
                    acc[i][j] = __builtin_amdgcn_mfma_f32_16x16x32_bf16(af[i], bf[j], acc[i][j], 0, 0, 0);
        }
    }

#pragma unroll
    for (int i = 0; i < 2; ++i)
#pragma unroll
        for (int j = 0; j < 4; ++j) {
            int col = bn + j * 16 + lm;
            float b = bias[col];
#pragma unroll
            for (int r = 0; r < 4; ++r) {
                int row = bm + w * 32 + i * 16 + quad * 4 + r;
                out[(size_t)row * HID + col] = acc[i][j][r] + b;
            }
        }
}

// ---------------- V sums from transposed bf16 V: wave per (n,h,d) row ----------------
__global__ __launch_bounds__(256) void vsum_kernel(const ushort_t* __restrict__ vtb,
    float* __restrict__ vwin, float* __restrict__ vgwin)
{
    int wid  = blockIdx.x * 4 + (threadIdx.x >> 6);   // 0..4095 = (n*NH+h)*HD+d
    int lane = threadIdx.x & 63;
    bf16x8 v = *(const bf16x8*)&vtb[(size_t)wid * WIN + lane * 8];
    float s = 0.f;
#pragma unroll
    for (int e = 0; e < 8; ++e) s += (float)v[e];
    float sg = ((lane & 3) == 0) ? (float)v[0] : 0.f;  // j = lane*8, j%32==0 iff lane%4==0
#pragma unroll
    for (int off = 1; off < 64; off <<= 1) {
        s  += __shfl_xor(s,  off);
        sg += __shfl_xor(sg, off);
    }
    if (lane == 0) { vwin[wid] = s; vgwin[wid] = sg; }
}

// ---------------- MFMA flash attention: S^T formulation, trimmed softmax VALU ----------------
// Grid (16 qtiles of 32, 16 heads, 4 windows) = 1024 blocks, 128 thr = 2 waves.
// S^T = K.Q^T: C-layout gives each lane 4 CONSECUTIVE keys of one query -> P
// stores are one ds_write_b64 per jt. Softmax VALU trimmed: raw v_exp_f32 on
// pre-scaled scores (SCALE*log2e folded), denominator accumulates UNROUNDED p
// (RNE is unbiased; inconsistency ~1.3e-5 relative on l~2100 -> negligible).
__global__ __launch_bounds__(128) void attn_mfma_kernel(
    const ushort_t* __restrict__ qb, const ushort_t* __restrict__ kb,
    const ushort_t* __restrict__ vtb,
    const float* __restrict__ vwin, const float* __restrict__ vgwin,
    ushort_t* __restrict__ ath)
{
    __shared__ __align__(16) ushort_t sK[64 * 64];    // [key][8 chunks of 8 d], swizzled
    __shared__ __align__(16) ushort_t sVt[64 * 64];   // [d][8 chunks of 8 j], swizzled
    __shared__ __align__(16) ushort_t sP[2][16 * 68]; // per-wave P[q][key], 68-padded rows
    __shared__ float sPe[48];
    __shared__ float sAe[64];
    __shared__ float sLe0;

    const int tid  = threadIdx.x;
    const int lane = tid & 63;
    const int w    = tid >> 6;     // 0..1
    const int quad = lane >> 4;
    const int lm   = lane & 15;
    const int tile = blockIdx.x;   // 0..15
    const int h    = blockIdx.y;
    const int n    = blockIdx.z;

    const ushort_t* kbase = &kb[(size_t)(n * WIN) * HID + h * HD];
    const ushort_t* vbase = &vtb[(size_t)(n * NH + h) * HD * WIN];

    const size_t qrow = (size_t)(n * WIN + tile * 32 + w * 16 + lm);
    const bf16x8 aq0 = *(const bf16x8*)&qb[qrow * HID + h * HD + quad * 8];
    const bf16x8 aq1 = *(const bf16x8*)&qb[qrow * HID + h * HD + 32 + quad * 8];

    f32x4 acc[4];
#pragma unroll
    for (int dt = 0; dt < 4; ++dt) acc[dt] = {0.f, 0.f, 0.f, 0.f};
    float lac = 0.f;                       // denominator partial for query lm
    // query global <=> (tile*32 + w*16 + lm) % 32 == 0 <=> w==0 && lm==0
    const bool qgl = (w == 0) && (lm == 0);

    ushort_t* sPw = sP[w];

    for (int c = 0; c < 8; ++c) {
        __syncthreads();
        // stage 64 keys of K + 64 d-rows of Vt: 512 chunks each, 4/thread each
#pragma unroll
        for (int t = 0; t < 4; ++t) {
            int c2 = tid + t * 128;
            int key = c2 >> 3, ck = c2 & 7, gc = ck ^ (key & 7);
            async16(&kbase[(size_t)(c * 64 + key) * HID + gc * 8], &sK[c2 * 8]);
            int dd = c2 >> 3, sl = c2 & 7, gj = sl ^ (dd & 7);
            async16(&vbase[(size_t)dd * WIN + c * 64 + gj * 8], &sVt[c2 * 8]);
        }
        asm volatile("s_waitcnt vmcnt(0)" ::: "memory");
        __syncthreads();

        // ---- S^T = K.Q^T + softmax numerators (shift m=0 safe: |s| < ~4) ----
#pragma unroll
        for (int jt = 0; jt < 4; ++jt) {
            int key = jt * 16 + lm;
            bf16x8 ak0 = *(const bf16x8*)&sK[key * 64 + ((quad) ^ (key & 7)) * 8];
            bf16x8 ak1 = *(const bf16x8*)&sK[key * 64 + ((4 + quad) ^ (key & 7)) * 8];
            f32x4 s = {0.f, 0.f, 0.f, 0.f};
            s = __builtin_amdgcn_mfma_f32_16x16x32_bf16(ak0, aq0, s, 0, 0, 0);
            s = __builtin_amdgcn_mfma_f32_16x16x32_bf16(ak1, aq1, s, 0, 0, 0);
            // s[r]: key = jt*16 + quad*4 + r, query = lm
            const bool kg = ((jt & 1) == 0) && (quad == 0);  // key%32==0 needs r==0 too
            ushort4 p4;
#pragma unroll
            for (int r = 0; r < 4; ++r) {
                float sv = s[r] * SCALE_LOG2E;
                if (qgl && kg && r == 0) sv += sv;   // in-window global pair: 2x score
                float p = EXP2F(sv);
                lac += p;                            // unrounded denominator
                ((ushort_t*)&p4)[r] = f32_to_bf16_rne(p);
            }
            // P[q=lm][key=jt*16+quad*4 .. +3] -> one 8B LDS store
            *(ushort4*)&sPw[lm * 68 + jt * 16 + quad * 4] = p4;
        }

        // ---- PV: P (A-layout, contiguous row read) x Vt (B-layout) ----
        bf16x8 pf[2];
        pf[0] = *(const bf16x8*)&sPw[lm * 68 + quad * 8];
        pf[1] = *(const bf16x8*)&sPw[lm * 68 + 32 + quad * 8];
#pragma unroll
        for (int dt = 0; dt < 4; ++dt) {
            int d = dt * 16 + lm;
#pragma unroll
            for (int jc = 0; jc < 2; ++jc) {
                bf16x8 vf = *(const bf16x8*)&sVt[d * 64 + (((jc * 4 + quad) ^ (d & 7))) * 8];
                acc[dt] = __builtin_amdgcn_mfma_f32_16x16x32_bf16(pf[jc], vf, acc[dt], 0, 0, 0);
            }
        }
    }

    // ---- denominator: reduce over the 4 quads (each covered disjoint keys) ----
    float lred = lac;
    lred += __shfl_xor(lred, 16);
    lred += __shfl_xor(lred, 32);   // all lanes with same lm now hold l[query=lm]

    // ---- out-of-window global keys for the 1 global query of this block ----
    __syncthreads();
    if (tid < 48) {
        int kk = tid;
        int g = kk + (kk >= n * 16 ? 16 : 0);   // skip in-window globals
        const ushort_t* qr = &qb[(size_t)(n * WIN + tile * 32) * HID + h * HD];
        const ushort_t* kr = &kb[(size_t)(g * GSTRIDE) * HID + h * HD];
        float dot = 0.f;
#pragma unroll
        for (int dc = 0; dc < 8; ++dc) {
            bf16x8 qv = *(const bf16x8*)&qr[dc * 8];
            bf16x8 kv = *(const bf16x8*)&kr[dc * 8];
#pragma unroll
            for (int e = 0; e < 8; ++e) dot += (float)qv[e] * (float)kv[e];
        }
        sPe[tid] = __expf(dot * SCALE);
    }
    __syncthreads();
    if (tid < 64) {
        int d = tid;
        float a = 0.f;
        for (int kk = 0; kk < 48; ++kk) {
            int g = kk + (kk >= n * 16 ? 16 : 0);
            int gwin = g >> 4, jj = (g & 15) * GSTRIDE;
            a += sPe[kk] *
                 bf16_to_f32(vtb[((size_t)(gwin * NH + h) * HD + d) * WIN + jj]);
        }
        sAe[d] = a;
    } else if (tid == 64) {
        float s = 0.f;
        for (int kk = 0; kk < 48; ++kk) s += sPe[kk];
        sLe0 = s;
    }
    __syncthreads();

    // ---- vrest inline from the vwin/vgwin tables (16 KB, L1-hot) ----
    float vr_ng_r[4], vr_g_r[4];
#pragma unroll
    for (int dt = 0; dt < 4; ++dt) {
        int d = dt * 16 + lm;
        float vall = 0.f, vgall = 0.f;
#pragma unroll
        for (int n2 = 0; n2 < NW; ++n2) {
            vall  += vwin [(n2 * NH + h) * HD + d];
            vgall += vgwin[(n2 * NH + h) * HD + d];
        }
        float w_  = vwin [(n * NH + h) * HD + d];
        float gw_ = vgwin[(n * NH + h) * HD + d];
        vr_ng_r[dt] = vall - w_;
        vr_g_r[dt]  = vall - w_ - (vgall - gw_);
    }

    // ---- epilogue: fold zero-score keys, normalize, write bf16 ----
#pragma unroll
    for (int r = 0; r < 4; ++r) {
        int qo = w * 16 + quad * 4 + r;
        int qwin = tile * 32 + qo;
        bool isg = ((qwin & (GSTRIDE - 1)) == 0);
        float lr = __shfl(lred, quad * 4 + r);     // l for this output row's query
        float l = lr + (float)(S_LEN - WIN);       // exp(0)=1 per non-attended key
        if (isg) l += sLe0 - 48.0f;                // 48 attended keys replace zeros
        float invl = 1.f / l;
        size_t row = (size_t)(n * WIN + qwin) * HID + h * HD;
#pragma unroll
        for (int dt = 0; dt < 4; ++dt) {
            int d = dt * 16 + lm;
            float o = acc[dt][r] + (isg ? (vr_g_r[dt] + sAe[d]) : vr_ng_r[dt]);
            ath[row + d] = f32_to_bf16_rne(o * invl);
        }
    }
}

extern "C" void kernel_launch(void* const* d_in, const int* in_sizes, int n_in,
                              void* d_out, int out_size, void* d_ws, size_t ws_size,
                              hipStream_t stream) {
    const float* x   = (const float*)d_in[0];
    const float* wq  = (const float*)d_in[1];
    const float* bq  = (const float*)d_in[2];
    const float* wk  = (const float*)d_in[3];
    const float* bk_ = (const float*)d_in[4];
    const float* wv  = (const float*)d_in[5];
    const float* bv  = (const float*)d_in[6];
    const float* wo  = (const float*)d_in[7];
    const float* bo  = (const float*)d_in[8];
    float* out = (float*)d_out;

    const size_t M2 = 2u * 1024 * 1024, M1 = 1024 * 1024;
    float* ws = (float*)d_ws;
    float* vwin  = ws;                       // 4096 floats
    float* vgwin = vwin + NW * NH * HD;      // 4096 floats
    ushort_t* us = (ushort_t*)(ws + 16384);
    ushort_t* xb  = us;            // 4 MB
    ushort_t* wqb = xb + M2;       ushort_t* wkb = wqb + M1;
    ushort_t* wvb = wkb + M1;      ushort_t* wob = wvb + M1;
    ushort_t* qb  = wob + M1;      // 4 MB
    ushort_t* kb  = qb + M2;       // 4 MB
    ushort_t* vtb = kb + M2;       // 4 MB
    ushort_t* ath = vtb + M2;      // 4 MB

    CastJobs jobs;
    jobs.in[0] = x;  jobs.hi[0] = xb;  jobs.n4[0] = (int)(M2 / 4);
    jobs.in[1] = wq; jobs.hi[1] = wqb; jobs.n4[1] = (int)(M1 / 4);
    jobs.in[2] = wk; jobs.hi[2] = wkb; jobs.n4[2] = (int)(M1 / 4);
    jobs.in[3] = wv; jobs.hi[3] = wvb; jobs.n4[3] = (int)(M1 / 4);
    jobs.in[4] = wo; jobs.hi[4] = wob; jobs.n4[4] = (int)(M1 / 4);
    cast_all_kernel<<<dim3(2048, 5), 256, 0, stream>>>(jobs);

    // fused QKV: 128x64 blocks, BK=64, grid (3 segs x 16 cols) x 16 rows = 768 blocks
    gemm_qkv_kernel<<<dim3(48, 16), 128, 0, stream>>>(
        xb, wqb, bq, wkb, bk_, wvb, bv, qb, kb, vtb);

    // V sums from vtb: 4096 waves, one per (n,h,d) row
    vsum_kernel<<<1024, 256, 0, stream>>>(vtb, vwin, vgwin);

    // attention: 1024 blocks (4/CU), 128 threads
    attn_mfma_kernel<<<dim3(16, NH, NW), 128, 0, stream>>>(
        qb, kb, vtb, vwin, vgwin, ath);

    // out projection: 64x64 x K=1024, BK=64 + fused bias, 512 blocks (2/CU)
    gemm_out_kernel<<<dim3(16, 32), 128, 0, stream>>>(ath, wob, bo, out);
}

// Round 13
// 150.561 us; speedup vs baseline: 1.4149x; 1.0056x over previous
//
#include <hip/hip_runtime.h>
#include <hip/hip_bf16.h>

#define S_LEN   2048
#define HID     1024
#define NH      16
#define HD      64
#define WIN     512
#define NW      4
#define NG      64
#define GSTRIDE 32
#define SCALE   0.125f               // 64^-0.5
#define SCALE_LOG2E 0.180336880f    // 0.125 * log2(e)

#if __has_builtin(__builtin_amdgcn_exp2f)
#define EXP2F(x) __builtin_amdgcn_exp2f(x)
#else
#define EXP2F(x) __expf((x) * 0.6931471805599453f)
#endif

typedef __bf16 bf16x2 __attribute__((ext_vector_type(2)));
typedef __bf16 bf16x8 __attribute__((ext_vector_type(8)));
typedef float  f32x4  __attribute__((ext_vector_type(4)));
typedef unsigned short ushort_t;

// ---------------- fp32 -> bf16 helpers ----------------
__device__ __forceinline__ ushort_t f32_to_bf16_rne(float f) {
    unsigned int u = __float_as_uint(f);
    u = u + 0x7FFFu + ((u >> 16) & 1u);
    return (ushort_t)(u >> 16);
}
__device__ __forceinline__ float bf16_to_f32(ushort_t h) {
    return __uint_as_float(((unsigned int)h) << 16);
}
// packed conversion: gfx950 HW v_cvt_pk_bf16_f32 (RNE), 2 values/instruction
#if __has_builtin(__builtin_amdgcn_cvt_pk_bf16_f32)
__device__ __forceinline__ unsigned int pk_bf16(float a, float b) {
    bf16x2 t = __builtin_amdgcn_cvt_pk_bf16_f32(a, b);
    return __builtin_bit_cast(unsigned int, t);
}
#else
__device__ __forceinline__ unsigned int pk_bf16(float a, float b) {
    return (unsigned int)f32_to_bf16_rne(a) | ((unsigned int)f32_to_bf16_rne(b) << 16);
}
#endif

// ---------------- batched cast: 5 tensors fp32 -> bf16 in one launch ----------------
struct CastJobs {
    const float* in[5];
    ushort_t* hi[5];
    int n4[5];
};

__global__ __launch_bounds__(256) void cast_all_kernel(CastJobs jobs) {
    int j = blockIdx.y;
    int i = blockIdx.x * 256 + threadIdx.x;
    if (i >= jobs.n4[j]) return;
    float4 f = ((const float4*)jobs.in[j])[i];
    uint2 h;
    h.x = pk_bf16(f.x, f.y);
    h.y = pk_bf16(f.z, f.w);
    ((uint2*)jobs.hi[j])[i] = h;
}

// ---------------- async global -> LDS (16B per lane) ----------------
__device__ __forceinline__ void async16(const ushort_t* g, ushort_t* l) {
    __builtin_amdgcn_global_load_lds(
        (const __attribute__((address_space(1))) void*)g,
        (__attribute__((address_space(3))) void*)l, 16, 0, 0);
}

// ============== single-bf16 MFMA GEMM (LDS-staged) ==============
// R10 lesson: fragment-direct global loads are UNcoalesced -> keep LDS staging.

// --- QKV variant, BK=64 (R11 win): swizzle gc = kp ^ (row & 7); fragment slot
// = (sub*4 + quad) ^ (row & 7) -> 2-way bank aliasing (free).
// q output is PRE-SCALED by SCALE*log2(e): its only consumers (QK MFMA and the
// global-key dot) want the scaled score, so attention's hot loop drops a mul.
__global__ __launch_bounds__(128) void gemm_qkv_kernel(
    const ushort_t* __restrict__ xb,
    const ushort_t* __restrict__ wqb, const float* __restrict__ bq,
    const ushort_t* __restrict__ wkb, const float* __restrict__ bk,
    const ushort_t* __restrict__ wvb, const float* __restrict__ bv,
    ushort_t* __restrict__ qb, ushort_t* __restrict__ kb,
    ushort_t* __restrict__ vtb)
{
    __shared__ ushort_t sA[128 * 64];   // 16 KB
    __shared__ ushort_t sB[64 * 64];    //  8 KB
    const int tid  = threadIdx.x;
    const int lane = tid & 63;
    const int w    = tid >> 6;
    const int quad = lane >> 4, lm = lane & 15;
    const int seg  = blockIdx.x >> 4;
    const int bn   = (blockIdx.x & 15) * 64;
    const int bm   = blockIdx.y * 128;

    const ushort_t* B  = (seg == 0) ? wqb : (seg == 1) ? wkb : wvb;
    const float* bias  = (seg == 0) ? bq  : (seg == 1) ? bk  : bv;

    f32x4 acc[4][4];
#pragma unroll
    for (int i = 0; i < 4; ++i)
#pragma unroll
        for (int j = 0; j < 4; ++j) acc[i][j] = {0.f, 0.f, 0.f, 0.f};

    for (int k0 = 0; k0 < HID; k0 += 64) {
        __syncthreads();
#pragma unroll
        for (int t = 0; t < 8; ++t) {          // A: 1024 chunks, 8/thread
            int c = tid + t * 128;
            int row = c >> 3, kp = c & 7, gc = kp ^ (row & 7);
            async16(&xb[(size_t)(bm + row) * HID + k0 + gc * 8], &sA[c * 8]);
        }
#pragma unroll
        for (int t = 0; t < 4; ++t) {          // B: 512 chunks, 4/thread
            int c = tid + t * 128;
            int row = c >> 3, kp = c & 7, gc = kp ^ (row & 7);
            async16(&B[(size_t)(bn + row) * HID + k0 + gc * 8], &sB[c * 8]);
        }
        asm volatile("s_waitcnt vmcnt(0)" ::: "memory");
        __syncthreads();

        // two BK=32 sub-steps per staged tile
#pragma unroll
        for (int sub = 0; sub < 2; ++sub) {
            bf16x8 af[4], bf[4];
#pragma unroll
            for (int i = 0; i < 4; ++i) {
                int row = w * 64 + i * 16 + lm;
                int slot = (sub * 4 + quad) ^ (row & 7);
                af[i] = *(const bf16x8*)&sA[row * 64 + slot * 8];
            }
#pragma unroll
            for (int j = 0; j < 4; ++j) {
                int row = j * 16 + lm;
                int slot = (sub * 4 + quad) ^ (row & 7);
                bf[j] = *(const bf16x8*)&sB[row * 64 + slot * 8];
            }
#pragma unroll
            for (int i = 0; i < 4; ++i)
#pragma unroll
                for (int j = 0; j < 4; ++j)
                    acc[i][j] = __builtin_amdgcn_mfma_f32_16x16x32_bf16(af[i], bf[j], acc[i][j], 0, 0, 0);
        }
    }

    // epilogue: C/D layout col=lane&15, row=quad*4+reg
    const float qsc = (seg == 0) ? SCALE_LOG2E : 1.0f;
#pragma unroll
    for (int i = 0; i < 4; ++i)
#pragma unroll
        for (int j = 0; j < 4; ++j) {
            int col = bn + j * 16 + lm;
            float b = bias[col];
            int row0 = bm + w * 64 + i * 16 + quad * 4;
            if (seg == 2) {
                // transposed V: r=0..3 are consecutive jj -> one 8B store
                int hh = col >> 6, dd = col & 63, nn = row0 >> 9, jj = row0 & 511;
                uint2 v4;
                v4.x = pk_bf16(acc[i][j][0] + b, acc[i][j][1] + b);
                v4.y = pk_bf16(acc[i][j][2] + b, acc[i][j][3] + b);
                *(uint2*)&vtb[(((size_t)nn * NH + hh) * HD + dd) * WIN + jj] = v4;
            } else {
                ushort_t* dst = (seg == 0) ? qb : kb;
                unsigned int c01 = pk_bf16((acc[i][j][0] + b) * qsc, (acc[i][j][1] + b) * qsc);
                unsigned int c23 = pk_bf16((acc[i][j][2] + b) * qsc, (acc[i][j][3] + b) * qsc);
                dst[(size_t)(row0 + 0) * HID + col] = (ushort_t)(c01 & 0xFFFFu);
                dst[(size_t)(row0 + 1) * HID + col] = (ushort_t)(c01 >> 16);
                dst[(size_t)(row0 + 2) * HID + col] = (ushort_t)(c23 & 0xFFFFu);
                dst[(size_t)(row0 + 3) * HID + col] = (ushort_t)(c23 >> 16);
            }
        }
}

// --- out-proj: 64x64 x K=1024, BK=64, fused bias, fp32 out ---
__global__ __launch_bounds__(128) void gemm_out_kernel(
    const ushort_t* __restrict__ A, const ushort_t* __restrict__ B,
    const float* __restrict__ bias, float* __restrict__ out)
{
    __shared__ ushort_t sA[64 * 64];   // 8 KB
    __shared__ ushort_t sB[64 * 64];   // 8 KB
    const int tid  = threadIdx.x;
    const int lane = tid & 63;
    const int w    = tid >> 6;
    const int quad = lane >> 4, lm = lane & 15;
    const int bn   = blockIdx.x * 64;
    const int bm   = blockIdx.y * 64;

    f32x4 acc[2][4];   // wave tile 32x64
#pragma unroll
    for (int i = 0; i < 2; ++i)
#pragma unroll
        for (int j = 0; j < 4; ++j) acc[i][j] = {0.f, 0.f, 0.f, 0.f};

    for (int k0 = 0; k0 < HID; k0 += 64) {
        __syncthreads();
#pragma unroll
        for (int t = 0; t < 4; ++t) {          // A,B: 512 chunks each, 4/thread
            int c = tid + t * 128;
            int row = c >> 3, kp = c & 7, gc = kp ^ (row & 7);
            async16(&A[(size_t)(bm + row) * HID + k0 + gc * 8], &sA[c * 8]);
            async16(&B[(size_t)(bn + row) * HID + k0 + gc * 8], &sB[c * 8]);
        }
        asm volatile("s_waitcnt vmcnt(0)" ::: "memory");
        __syncthreads();

#pragma unroll
        for (int sub = 0; sub < 2; ++sub) {
            bf16x8 af[2], bf[4];
#pragma unroll
            for (int i = 0; i < 2; ++i) {
                int row = w * 32 + i * 16 + lm;
                int slot = (sub * 4 + quad) ^ (row & 7);
                af[i] = *(const bf16x8*)&sA[row * 64 + slot * 8];
            }
#pragma unroll
            for (int j = 0; j < 4; ++j) {
                int row = j * 16 + lm;
                int slot = (sub * 4 + quad) ^ (row & 7);
                bf[j] = *(const bf16x8*)&sB[row * 64 + slot * 8];
            }
#pragma unroll
            for (int i = 0; i < 2; ++i)
#pragma unroll
                for (int j = 0; j < 4; ++j)
                    acc[i][j] = __builtin_amdgcn_mfma_f32_16x16x32_bf16(af[i], bf[j], acc[i][j], 0, 0, 0);
        }
    }

#pragma unroll
    for (int i = 0; i < 2; ++i)
#pragma unroll
        for (int j = 0; j < 4; ++j) {
            int col = bn + j * 16 + lm;
            float b = bias[col];
#pragma unroll
            for (int r = 0; r < 4; ++r) {
                int row = bm + w * 32 + i * 16 + quad * 4 + r;
                out[(size_t)row * HID + col] = acc[i][j][r] + b;
            }
        }
}

// ---------------- V sums from transposed bf16 V: wave per (n,h,d) row ----------------
__global__ __launch_bounds__(256) void vsum_kernel(const ushort_t* __restrict__ vtb,
    float* __restrict__ vwin, float* __restrict__ vgwin)
{
    int wid  = blockIdx.x * 4 + (threadIdx.x >> 6);   // 0..4095 = (n*NH+h)*HD+d
    int lane = threadIdx.x & 63;
    bf16x8 v = *(const bf16x8*)&vtb[(size_t)wid * WIN + lane * 8];
    float s = 0.f;
#pragma unroll
    for (int e = 0; e < 8; ++e) s += (float)v[e];
    float sg = ((lane & 3) == 0) ? (float)v[0] : 0.f;  // j = lane*8, j%32==0 iff lane%4==0
#pragma unroll
    for (int off = 1; off < 64; off <<= 1) {
        s  += __shfl_xor(s,  off);
        sg += __shfl_xor(sg, off);
    }
    if (lane == 0) { vwin[wid] = s; vgwin[wid] = sg; }
}

// ---------------- MFMA flash attention: S^T formulation, HW pk-bf16, pre-scaled q ----------------
// Grid (16 qtiles of 32, 16 heads, 4 windows) = 1024 blocks, 128 thr = 2 waves.
// S^T = K.Q^T: C-layout gives each lane 4 CONSECUTIVE keys of one query -> P
// stores are one 8B LDS store per jt. qb is pre-scaled by SCALE*log2e, so
// scores go straight to v_exp_f32 (exp2). P conversion via v_cvt_pk_bf16_f32.
__global__ __launch_bounds__(128) void attn_mfma_kernel(
    const ushort_t* __restrict__ qb, const ushort_t* __restrict__ kb,
    const ushort_t* __restrict__ vtb,
    const float* __restrict__ vwin, const float* __restrict__ vgwin,
    ushort_t* __restrict__ ath)
{
    __shared__ __align__(16) ushort_t sK[64 * 64];    // [key][8 chunks of 8 d], swizzled
    __shared__ __align__(16) ushort_t sVt[64 * 64];   // [d][8 chunks of 8 j], swizzled
    __shared__ __align__(16) ushort_t sP[2][16 * 68]; // per-wave P[q][key], 68-padded rows
    __shared__ float sPe[48];
    __shared__ float sAe[64];
    __shared__ float sLe0;

    const int tid  = threadIdx.x;
    const int lane = tid & 63;
    const int w    = tid >> 6;     // 0..1
    const int quad = lane >> 4;
    const int lm   = lane & 15;
    const int tile = blockIdx.x;   // 0..15
    const int h    = blockIdx.y;
    const int n    = blockIdx.z;

    const ushort_t* kbase = &kb[(size_t)(n * WIN) * HID + h * HD];
    const ushort_t* vbase = &vtb[(size_t)(n * NH + h) * HD * WIN];

    const size_t qrow = (size_t)(n * WIN + tile * 32 + w * 16 + lm);
    const bf16x8 aq0 = *(const bf16x8*)&qb[qrow * HID + h * HD + quad * 8];
    const bf16x8 aq1 = *(const bf16x8*)&qb[qrow * HID + h * HD + 32 + quad * 8];

    f32x4 acc[4];
#pragma unroll
    for (int dt = 0; dt < 4; ++dt) acc[dt] = {0.f, 0.f, 0.f, 0.f};
    float lac = 0.f;                       // denominator partial for query lm
    // query global <=> (tile*32 + w*16 + lm) % 32 == 0 <=> w==0 && lm==0
    const bool qgl = (w == 0) && (lm == 0);

    ushort_t* sPw = sP[w];

    for (int c = 0; c < 8; ++c) {
        __syncthreads();
        // stage 64 keys of K + 64 d-rows of Vt: 512 chunks each, 4/thread each
#pragma unroll
        for (int t = 0; t < 4; ++t) {
            int c2 = tid + t * 128;
            int key = c2 >> 3, ck = c2 & 7, gc = ck ^ (key & 7);
            async16(&kbase[(size_t)(c * 64 + key) * HID + gc * 8], &sK[c2 * 8]);
            int dd = c2 >> 3, sl = c2 & 7, gj = sl ^ (dd & 7);
            async16(&vbase[(size_t)dd * WIN + c * 64 + gj * 8], &sVt[c2 * 8]);
        }
        asm volatile("s_waitcnt vmcnt(0)" ::: "memory");
        __syncthreads();

        // ---- S^T = K.Q^T + softmax numerators (shift m=0 safe: |s| < ~4) ----
#pragma unroll
        for (int jt = 0; jt < 4; ++jt) {
            int key = jt * 16 + lm;
            bf16x8 ak0 = *(const bf16x8*)&sK[key * 64 + ((quad) ^ (key & 7)) * 8];
            bf16x8 ak1 = *(const bf16x8*)&sK[key * 64 + ((4 + quad) ^ (key & 7)) * 8];
            f32x4 s = {0.f, 0.f, 0.f, 0.f};
            s = __builtin_amdgcn_mfma_f32_16x16x32_bf16(ak0, aq0, s, 0, 0, 0);
            s = __builtin_amdgcn_mfma_f32_16x16x32_bf16(ak1, aq1, s, 0, 0, 0);
            // s[r]: key = jt*16 + quad*4 + r, query = lm  (already log2e-scaled)
            const bool kg = ((jt & 1) == 0) && (quad == 0);  // key%32==0 needs r==0 too
            float p[4];
#pragma unroll
            for (int r = 0; r < 4; ++r) {
                float sv = s[r];
                if (qgl && kg && r == 0) sv += sv;   // in-window global pair: 2x score
                p[r] = EXP2F(sv);
                lac += p[r];                         // unrounded denominator
            }
            uint2 pp;
            pp.x = pk_bf16(p[0], p[1]);
            pp.y = pk_bf16(p[2], p[3]);
            // P[q=lm][key=jt*16+quad*4 .. +3] -> one 8B LDS store
            *(uint2*)&sPw[lm * 68 + jt * 16 + quad * 4] = pp;
        }

        // ---- PV: P (A-layout, contiguous row read) x Vt (B-layout) ----
        bf16x8 pf[2];
        pf[0] = *(const bf16x8*)&sPw[lm * 68 + quad * 8];
        pf[1] = *(const bf16x8*)&sPw[lm * 68 + 32 + quad * 8];
#pragma unroll
        for (int dt = 0; dt < 4; ++dt) {
            int d = dt * 16 + lm;
#pragma unroll
            for (int jc = 0; jc < 2; ++jc) {
                bf16x8 vf = *(const bf16x8*)&sVt[d * 64 + (((jc * 4 + quad) ^ (d & 7))) * 8];
                acc[dt] = __builtin_amdgcn_mfma_f32_16x16x32_bf16(pf[jc], vf, acc[dt], 0, 0, 0);
            }
        }
    }

    // ---- denominator: reduce over the 4 quads (each covered disjoint keys) ----
    float lred = lac;
    lred += __shfl_xor(lred, 16);
    lred += __shfl_xor(lred, 32);   // all lanes with same lm now hold l[query=lm]

    // ---- out-of-window global keys for the 1 global query of this block ----
    __syncthreads();
    if (tid < 48) {
        int kk = tid;
        int g = kk + (kk >= n * 16 ? 16 : 0);   // skip in-window globals
        const ushort_t* qr = &qb[(size_t)(n * WIN + tile * 32) * HID + h * HD];
        const ushort_t* kr = &kb[(size_t)(g * GSTRIDE) * HID + h * HD];
        float dot = 0.f;
#pragma unroll
        for (int dc = 0; dc < 8; ++dc) {
            bf16x8 qv = *(const bf16x8*)&qr[dc * 8];
            bf16x8 kv = *(const bf16x8*)&kr[dc * 8];
#pragma unroll
            for (int e = 0; e < 8; ++e) dot += (float)qv[e] * (float)kv[e];
        }
        sPe[tid] = EXP2F(dot);    // q pre-scaled by SCALE*log2e
    }
    __syncthreads();
    if (tid < 64) {
        int d = tid;
        float a = 0.f;
        for (int kk = 0; kk < 48; ++kk) {
            int g = kk + (kk >= n * 16 ? 16 : 0);
            int gwin = g >> 4, jj = (g & 15) * GSTRIDE;
            a += sPe[kk] *
                 bf16_to_f32(vtb[((size_t)(gwin * NH + h) * HD + d) * WIN + jj]);
        }
        sAe[d] = a;
    } else if (tid == 64) {
        float s = 0.f;
        for (int kk = 0; kk < 48; ++kk) s += sPe[kk];
        sLe0 = s;
    }
    __syncthreads();

    // ---- vrest inline from the vwin/vgwin tables (16 KB, L1-hot) ----
    float vr_ng_r[4], vr_g_r[4];
#pragma unroll
    for (int dt = 0; dt < 4; ++dt) {
        int d = dt * 16 + lm;
        float vall = 0.f, vgall = 0.f;
#pragma unroll
        for (int n2 = 0; n2 < NW; ++n2) {
            vall  += vwin [(n2 * NH + h) * HD + d];
            vgall += vgwin[(n2 * NH + h) * HD + d];
        }
        float w_  = vwin [(n * NH + h) * HD + d];
        float gw_ = vgwin[(n * NH + h) * HD + d];
        vr_ng_r[dt] = vall - w_;
        vr_g_r[dt]  = vall - w_ - (vgall - gw_);
    }

    // ---- epilogue: fold zero-score keys, normalize, write bf16 ----
#pragma unroll
    for (int r = 0; r < 4; ++r) {
        int qo = w * 16 + quad * 4 + r;
        int qwin = tile * 32 + qo;
        bool isg = ((qwin & (GSTRIDE - 1)) == 0);
        float lr = __shfl(lred, quad * 4 + r);     // l for this output row's query
        float l = lr + (float)(S_LEN - WIN);       // exp(0)=1 per non-attended key
        if (isg) l += sLe0 - 48.0f;                // 48 attended keys replace zeros
        float invl = 1.f / l;
        size_t row = (size_t)(n * WIN + qwin) * HID + h * HD;
#pragma unroll
        for (int dt = 0; dt < 4; ++dt) {
            int d = dt * 16 + lm;
            float o = acc[dt][r] + (isg ? (vr_g_r[dt] + sAe[d]) : vr_ng_r[dt]);
            ath[row + d] = f32_to_bf16_rne(o * invl);
        }
    }
}

extern "C" void kernel_launch(void* const* d_in, const int* in_sizes, int n_in,
                              void* d_out, int out_size, void* d_ws, size_t ws_size,
                              hipStream_t stream) {
    const float* x   = (const float*)d_in[0];
    const float* wq  = (const float*)d_in[1];
    const float* bq  = (const float*)d_in[2];
    const float* wk  = (const float*)d_in[3];
    const float* bk_ = (const float*)d_in[4];
    const float* wv  = (const float*)d_in[5];
    const float* bv  = (const float*)d_in[6];
    const float* wo  = (const float*)d_in[7];
    const float* bo  = (const float*)d_in[8];
    float* out = (float*)d_out;

    const size_t M2 = 2u * 1024 * 1024, M1 = 1024 * 1024;
    float* ws = (float*)d_ws;
    float* vwin  = ws;                       // 4096 floats
    float* vgwin = vwin + NW * NH * HD;      // 4096 floats
    ushort_t* us = (ushort_t*)(ws + 16384);
    ushort_t* xb  = us;            // 4 MB
    ushort_t* wqb = xb + M2;       ushort_t* wkb = wqb + M1;
    ushort_t* wvb = wkb + M1;      ushort_t* wob = wvb + M1;
    ushort_t* qb  = wob + M1;      // 4 MB
    ushort_t* kb  = qb + M2;       // 4 MB
    ushort_t* vtb = kb + M2;       // 4 MB
    ushort_t* ath = vtb + M2;      // 4 MB

    CastJobs jobs;
    jobs.in[0] = x;  jobs.hi[0] = xb;  jobs.n4[0] = (int)(M2 / 4);
    jobs.in[1] = wq; jobs.hi[1] = wqb; jobs.n4[1] = (int)(M1 / 4);
    jobs.in[2] = wk; jobs.hi[2] = wkb; jobs.n4[2] = (int)(M1 / 4);
    jobs.in[3] = wv; jobs.hi[3] = wvb; jobs.n4[3] = (int)(M1 / 4);
    jobs.in[4] = wo; jobs.hi[4] = wob; jobs.n4[4] = (int)(M1 / 4);
    cast_all_kernel<<<dim3(2048, 5), 256, 0, stream>>>(jobs);

    // fused QKV: 128x64 blocks, BK=64, grid (3 segs x 16 cols) x 16 rows = 768 blocks
    gemm_qkv_kernel<<<dim3(48, 16), 128, 0, stream>>>(
        xb, wqb, bq, wkb, bk_, wvb, bv, qb, kb, vtb);

    // V sums from vtb: 4096 waves, one per (n,h,d) row
    vsum_kernel<<<1024, 256, 0, stream>>>(vtb, vwin, vgwin);

    // attention: 1024 blocks (4/CU), 128 threads
    attn_mfma_kernel<<<dim3(16, NH, NW), 128, 0, stream>>>(
        qb, kb, vtb, vwin, vgwin, ath);

    // out projection: 64x64 x K=1024, BK=64 + fused bias, 512 blocks (2/CU)
    gemm_out_kernel<<<dim3(16, 32), 128, 0, stream>>>(ath, wob, bo, out);
}